// Round 3
// baseline (992.872 us; speedup 1.0000x reference)
//
#include <hip/hip_runtime.h>

typedef __attribute__((ext_vector_type(8))) short bf16x8;
typedef __attribute__((ext_vector_type(4))) short bf16x4;
typedef __attribute__((ext_vector_type(4))) float f32x4;

__device__ __forceinline__ float bf2f(ushort u) {
  union { unsigned int i; float f; } v; v.i = ((unsigned int)u) << 16; return v.f;
}
__device__ __forceinline__ ushort f2bf(float f) {
  union { float f; unsigned int i; } v; v.f = f;
  unsigned int x = v.i;
  unsigned int r = (x + 0x7fffu + ((x >> 16) & 1u)) >> 16;
  return (ushort)r;
}

// ---------------------------------------------------------------- utilities
__global__ void zero_f32(float* p, int n) {
  int i = blockIdx.x * 256 + threadIdx.x;
  if (i < n) p[i] = 0.f;
}

// Pack W[co][ci][ky][kx] (fp32) -> Wp[tap][cic][cf][lane][8] (bf16)
// A-frag layout for mfma_f32_16x16x32_bf16: lane l holds A[row=l&15][k=(l>>4)*8+j]
__global__ void pack_w(const float* __restrict__ W, ushort* __restrict__ Wp, int Cin) {
  int ncic = Cin >> 5;
  int total = 9 * ncic * 8 * 64 * 8;
  for (int idx = blockIdx.x * 256 + threadIdx.x; idx < total; idx += gridDim.x * 256) {
    int j = idx & 7;
    int l = (idx >> 3) & 63;
    int cf = (idx >> 9) & 7;
    int rest = idx >> 12;
    int cic = rest % ncic;
    int tap = rest / ncic;
    int co = cf * 16 + (l & 15);
    int ci = cic * 32 + ((l >> 4) * 8) + j;
    int ky = tap / 3, kx = tap % 3;
    Wp[idx] = f2bf(W[((co * Cin + ci) * 3 + ky) * 3 + kx]);
  }
}

// NCHW fp32 [8][64][65536] -> NHWC bf16 [8][65536][64]
__global__ __launch_bounds__(256)
void nchw2nhwc(const float* __restrict__ in, ushort* __restrict__ out) {
  const int n  = blockIdx.y;
  const int p0 = blockIdx.x << 6;
  const int tid = threadIdx.x;
  __shared__ ushort t[64 * 72];
  {
    int c  = tid >> 2;
    int pq = (tid & 3) << 4;
    const float* ip = in + (((size_t)(n * 64 + c)) << 16) + p0 + pq;
#pragma unroll
    for (int k = 0; k < 4; ++k) {
      float4 f = *(const float4*)(ip + k * 4);
      int p = pq + k * 4;
      t[(p + 0) * 72 + c] = f2bf(f.x);
      t[(p + 1) * 72 + c] = f2bf(f.y);
      t[(p + 2) * 72 + c] = f2bf(f.z);
      t[(p + 3) * 72 + c] = f2bf(f.w);
    }
  }
  __syncthreads();
#pragma unroll
  for (int k = 0; k < 2; ++k) {
    int id = k * 256 + tid;
    int cj = id & 7, p = id >> 3;
    bf16x8 v = *(const bf16x8*)&t[p * 72 + cj * 8];
    *(bf16x8*)(out + ((((size_t)n << 16) + p0 + p) << 6) + cj * 8) = v;
  }
}

__device__ __forceinline__ bf16x8 bnrelu8(bf16x8 v, const float* __restrict__ coef, int c0) {
  float4 a0 = *(const float4*)(coef + c0);
  float4 a1 = *(const float4*)(coef + c0 + 4);
  float4 b0 = *(const float4*)(coef + 128 + c0);
  float4 b1 = *(const float4*)(coef + 128 + c0 + 4);
  bf16x8 r;
  r[0] = (short)f2bf(fmaxf(a0.x * bf2f((ushort)v[0]) + b0.x, 0.f));
  r[1] = (short)f2bf(fmaxf(a0.y * bf2f((ushort)v[1]) + b0.y, 0.f));
  r[2] = (short)f2bf(fmaxf(a0.z * bf2f((ushort)v[2]) + b0.z, 0.f));
  r[3] = (short)f2bf(fmaxf(a0.w * bf2f((ushort)v[3]) + b0.w, 0.f));
  r[4] = (short)f2bf(fmaxf(a1.x * bf2f((ushort)v[4]) + b1.x, 0.f));
  r[5] = (short)f2bf(fmaxf(a1.y * bf2f((ushort)v[5]) + b1.y, 0.f));
  r[6] = (short)f2bf(fmaxf(a1.z * bf2f((ushort)v[6]) + b1.z, 0.f));
  r[7] = (short)f2bf(fmaxf(a1.w * bf2f((ushort)v[7]) + b1.w, 0.f));
  return r;
}

// ---------------------------------------------------------------- conv core (NHWC)
// src NHWC bf16 [n][H*W][Cin]; out NHWC bf16 [n][H*W][128].
// Block: 64x * 2y * 128co, 4 waves = (cg in {0,1} co-halves) x (wy in {0,1} rows).
// 2-phase pipeline: LOADREG(next) -> COMPUTE(cur) -> WRITE(next) -> barrier.
// MODE 0: plain; MODE 1: relu(a*x+b) applied at LDS-write time (coef).
template<int MODE>
__global__ __launch_bounds__(256)
void conv_mfma(const ushort* __restrict__ src, const ushort* __restrict__ Wp,
               const float* __restrict__ bias, const float* __restrict__ coef,
               ushort* __restrict__ out, float* __restrict__ sSum, float* __restrict__ sSsq,
               int Cin, int H, int W)
{
  const int ncic = Cin >> 5;
  const int x0 = blockIdx.x << 6;
  const int y0 = blockIdx.y << 1;
  const int n  = blockIdx.z;
  const int tid = threadIdx.x;
  const int wv = tid >> 6, l = tid & 63, l15 = l & 15, l4 = l >> 4;
  const int cg = wv >> 1;      // co 64-group
  const int wy = wv & 1;       // output row within tile
  const int cg4 = cg << 2;     // cf base

  // two staging buffers [row4][xt66][ci32] = 16896 B each; epilogue reuses
  __shared__ __align__(16) ushort smem[2 * 8448];

  const size_t HW = (size_t)H * W;
  const ushort* srcn = src + (size_t)n * HW * Cin;

  f32x4 acc[4][4];
#pragma unroll
  for (int f = 0; f < 4; ++f)
#pragma unroll
    for (int xf = 0; xf < 4; ++xf) acc[f][xf] = (f32x4){0.f, 0.f, 0.f, 0.f};

  bf16x8 st[5];

  auto LOADREG = [&](int cic) {
#pragma unroll
    for (int it = 0; it < 5; ++it) {
      if (it < 4 || tid < 32) {
        int i = it * 256 + tid;
        int cj = i & 3, p = i >> 2;
        int row = p / 66, xt = p - row * 66;
        int ry = y0 + row - 1, gx = x0 + xt - 1;
        bf16x8 v = {};
        if ((unsigned)ry < (unsigned)H && (unsigned)gx < (unsigned)W)
          v = *(const bf16x8*)(srcn + ((size_t)ry * W + gx) * Cin + (cic << 5) + (cj << 3));
        st[it] = v;
      }
    }
  };

  auto WRITE = [&](ushort* buf, int cic) {
#pragma unroll
    for (int it = 0; it < 5; ++it) {
      if (it < 4 || tid < 32) {
        int i = it * 256 + tid;
        bf16x8 v = st[it];
        if (MODE == 1) {
          int cj = i & 3, p = i >> 2;
          int row = p / 66, xt = p - row * 66;
          int ry = y0 + row - 1, gx = x0 + xt - 1;
          if ((unsigned)ry < (unsigned)H && (unsigned)gx < (unsigned)W)
            v = bnrelu8(v, coef, (cic << 5) + (cj << 3));
        }
        *(bf16x8*)(buf + i * 8) = v;
      }
    }
  };

  auto COMPUTE = [&](const ushort* buf, int cic) {
    const ushort* lrow = buf + l15 * 32 + l4 * 8;
    const ushort* wp = Wp + ((size_t)cic * 8 + cg4) * 512 + (size_t)l * 8;
    const size_t tapstride = (size_t)ncic * 8 * 512;
    bf16x8 aC[4], bC[4], aN[4], bN[4];
#pragma unroll
    for (int f = 0; f < 4; ++f) aC[f] = *(const bf16x8*)(wp + f * 512);
#pragma unroll
    for (int xf = 0; xf < 4; ++xf)
      bC[xf] = *(const bf16x8*)(lrow + (wy * 66 + xf * 16) * 32);
#pragma unroll
    for (int tap = 0; tap < 9; ++tap) {
      if (tap < 8) {
        const int ky1 = (tap + 1) / 3, kx1 = (tap + 1) % 3;
#pragma unroll
        for (int f = 0; f < 4; ++f)
          aN[f] = *(const bf16x8*)(wp + (size_t)(tap + 1) * tapstride + f * 512);
#pragma unroll
        for (int xf = 0; xf < 4; ++xf)
          bN[xf] = *(const bf16x8*)(lrow + ((wy + ky1) * 66 + xf * 16 + kx1) * 32);
      }
#pragma unroll
      for (int f = 0; f < 4; ++f)
#pragma unroll
        for (int xf = 0; xf < 4; ++xf)
          acc[f][xf] = __builtin_amdgcn_mfma_f32_16x16x32_bf16(aC[f], bC[xf], acc[f][xf], 0, 0, 0);
#pragma unroll
      for (int f = 0; f < 4; ++f) aC[f] = aN[f];
#pragma unroll
      for (int xf = 0; xf < 4; ++xf) bC[xf] = bN[xf];
    }
  };

  // prologue
  LOADREG(0);
  WRITE(smem, 0);
  __syncthreads();

  int cur = 0;
  for (int cic = 0; cic < ncic; ++cic) {
    if (cic + 1 < ncic) LOADREG(cic + 1);
    COMPUTE(smem + cur * 8448, cic);
    if (cic + 1 < ncic) WRITE(smem + (cur ^ 1) * 8448, cic + 1);
    __syncthreads();
    cur ^= 1;
  }

  // ------------- epilogue: bias, stats, NHWC store via LDS transpose
  float smv[4][4] = {{0.f}}, sqv[4][4] = {{0.f}};
  ushort* eps = smem;   // [x64][co 136]
  for (int yr = 0; yr < 2; ++yr) {
    __syncthreads();
    if (wy == yr) {
#pragma unroll
      for (int f = 0; f < 4; ++f) {
        const int col = (cg << 6) + (f << 4) + (l4 << 2);
        float4 bv = *(const float4*)(bias + col);
#pragma unroll
        for (int xf = 0; xf < 4; ++xf) {
          float v0 = acc[f][xf][0] + bv.x;
          float v1 = acc[f][xf][1] + bv.y;
          float v2 = acc[f][xf][2] + bv.z;
          float v3 = acc[f][xf][3] + bv.w;
          smv[f][0] += v0; sqv[f][0] += v0 * v0;
          smv[f][1] += v1; sqv[f][1] += v1 * v1;
          smv[f][2] += v2; sqv[f][2] += v2 * v2;
          smv[f][3] += v3; sqv[f][3] += v3 * v3;
          bf16x4 u;
          u[0] = (short)f2bf(v0); u[1] = (short)f2bf(v1);
          u[2] = (short)f2bf(v2); u[3] = (short)f2bf(v3);
          *(bf16x4*)&eps[((xf << 4) + l15) * 136 + col] = u;
        }
      }
    }
    __syncthreads();
    {
      const int xx = tid >> 2, c0 = (tid & 3) << 5;
      ushort* op = out + ((size_t)n * HW + (size_t)(y0 + yr) * W + x0 + xx) * 128 + c0;
#pragma unroll
      for (int k = 0; k < 4; ++k)
        *(bf16x8*)(op + (k << 3)) = *(const bf16x8*)&eps[xx * 136 + c0 + (k << 3)];
    }
  }

  const int rep = (int)((blockIdx.z * gridDim.y + blockIdx.y) * gridDim.x + blockIdx.x) & 31;
#pragma unroll
  for (int f = 0; f < 4; ++f)
#pragma unroll
    for (int j = 0; j < 4; ++j) {
      float s = smv[f][j], q = sqv[f][j];
#pragma unroll
      for (int o = 1; o < 16; o <<= 1) { s += __shfl_xor(s, o); q += __shfl_xor(q, o); }
      if (l15 == 0) {
        int co = (cg << 6) + (f << 4) + (l4 << 2) + j;
        atomicAdd(&sSum[rep * 128 + co], s);
        atomicAdd(&sSsq[rep * 128 + co], q);
      }
    }
}

// ---------------------------------------------------------------- BN finalize
__global__ void bn_finalize(const float* __restrict__ sSum, const float* __restrict__ sSsq,
                            const float* __restrict__ g, const float* __restrict__ be,
                            float* __restrict__ coef, float invN)
{
  int c = threadIdx.x;  // 128
  float S = 0.f, Q = 0.f;
  for (int r = 0; r < 32; ++r) { S += sSum[r * 128 + c]; Q += sSsq[r * 128 + c]; }
  float m = S * invN;
  float v = Q * invN - m * m;
  float a = g[c] / sqrtf(v + 1e-5f);
  coef[c] = a;
  coef[128 + c] = be[c] - m * a;
}

// ---------------------------------------------------------------- fused bn_relu + skip out (NCHW fp32) + DWT (NHWC bf16)
// Block: 32c x 64x x 2 input rows. Reads skip_raw once.
__global__ __launch_bounds__(256)
void skip_dwt2(const ushort* __restrict__ skipRaw, const float* __restrict__ coef,
               float* __restrict__ outSkip, ushort* __restrict__ dwt)
{
  const int x0 = blockIdx.x << 6;       // 0,64,128,192
  const int oy = blockIdx.y;            // 0..127
  const int n  = blockIdx.z >> 2;
  const int ct = blockIdx.z & 3;        // c-tile of 32
  const int y0 = oy << 1;
  const int tid = threadIdx.x;
  __shared__ float t32[32 * 2 * 68];    // [c][r][x pad 68]

#pragma unroll
  for (int it = 0; it < 2; ++it) {
    int i = it * 256 + tid;             // 512 chunks: [r2][x64][cj4]
    int cj = i & 3, x = (i >> 2) & 63, r = i >> 8;
    int c0 = (ct << 5) + (cj << 3);
    bf16x8 v = *(const bf16x8*)(skipRaw + (((size_t)n << 16) + (size_t)(y0 + r) * 256 + x0 + x) * 128 + c0);
    float4 a0 = *(const float4*)(coef + c0);
    float4 a1 = *(const float4*)(coef + c0 + 4);
    float4 b0 = *(const float4*)(coef + 128 + c0);
    float4 b1 = *(const float4*)(coef + 128 + c0 + 4);
    float av[8] = {a0.x, a0.y, a0.z, a0.w, a1.x, a1.y, a1.z, a1.w};
    float bv[8] = {b0.x, b0.y, b0.z, b0.w, b1.x, b1.y, b1.z, b1.w};
    int cl = cj << 3;
#pragma unroll
    for (int k = 0; k < 8; ++k)
      t32[((cl + k) * 2 + r) * 68 + x] = fmaxf(av[k] * bf2f((ushort)v[k]) + bv[k], 0.f);
  }
  __syncthreads();

  // NCHW fp32 store (both rows)
  {
    int c = tid >> 3, x8 = (tid & 7) << 3;
    float* op = outSkip + (((size_t)(n * 128 + (ct << 5) + c)) << 16) + (size_t)y0 * 256 + x0 + x8;
#pragma unroll
    for (int r = 0; r < 2; ++r) {
      float4 r0 = *(const float4*)&t32[(c * 2 + r) * 68 + x8];
      float4 r1 = *(const float4*)&t32[(c * 2 + r) * 68 + x8 + 4];
      *(float4*)(op + (size_t)r * 256) = r0;
      *(float4*)(op + (size_t)r * 256 + 4) = r1;
    }
  }

  // DWT (threads 0..127): 32 ox x 4 cj
  if (tid < 128) {
    int cj = tid & 3, ox = tid >> 2;
    int cl = cj << 3;
    bf16x8 oA, oH, oV, oD;
#pragma unroll
    for (int k = 0; k < 8; ++k) {
      int c = cl + k;
      float p00 = t32[(c * 2 + 0) * 68 + 2 * ox];
      float p01 = t32[(c * 2 + 0) * 68 + 2 * ox + 1];
      float p10 = t32[(c * 2 + 1) * 68 + 2 * ox];
      float p11 = t32[(c * 2 + 1) * 68 + 2 * ox + 1];
      oA[k] = (short)f2bf((p00 + p01 + p10 + p11) * 0.5f);
      oH[k] = (short)f2bf((p00 + p01 - p10 - p11) * 0.5f);
      oV[k] = (short)f2bf((p00 - p01 + p10 - p11) * 0.5f);
      oD[k] = (short)f2bf((p00 - p01 - p10 + p11) * 0.5f);
    }
    size_t db = ((size_t)n * 16384 + (size_t)oy * 128 + (x0 >> 1) + ox) * 512 + (ct << 5) + cl;
    *(bf16x8*)(dwt + db)       = oA;
    *(bf16x8*)(dwt + db + 128) = oH;
    *(bf16x8*)(dwt + db + 256) = oV;
    *(bf16x8*)(dwt + db + 384) = oD;
  }
}

// ---------------------------------------------------------------- bn_relu + NHWC->NCHW fp32 out
__global__ __launch_bounds__(256)
void bn_transpose_out(const ushort* __restrict__ src, const float* __restrict__ coef,
                      float* __restrict__ dst, int H, int W)
{
  const int n  = blockIdx.z >> 2;
  const int cc = blockIdx.z & 3;
  const int x0 = blockIdx.x << 6;
  const int y  = blockIdx.y;
  const int tid = threadIdx.x;
  __shared__ float t[32 * 68];
  const size_t HW = (size_t)H * W;
  {
    int p = tid >> 2, cj = tid & 3;
    int c0 = (cc << 5) + (cj << 3);
    bf16x8 v = *(const bf16x8*)(src + ((size_t)n * HW + (size_t)y * W + x0 + p) * 128 + c0);
    float4 a0 = *(const float4*)(coef + c0);
    float4 a1 = *(const float4*)(coef + c0 + 4);
    float4 b0 = *(const float4*)(coef + 128 + c0);
    float4 b1 = *(const float4*)(coef + 128 + c0 + 4);
    int cl = cj << 3;
    t[(cl + 0) * 68 + p] = fmaxf(a0.x * bf2f((ushort)v[0]) + b0.x, 0.f);
    t[(cl + 1) * 68 + p] = fmaxf(a0.y * bf2f((ushort)v[1]) + b0.y, 0.f);
    t[(cl + 2) * 68 + p] = fmaxf(a0.z * bf2f((ushort)v[2]) + b0.z, 0.f);
    t[(cl + 3) * 68 + p] = fmaxf(a0.w * bf2f((ushort)v[3]) + b0.w, 0.f);
    t[(cl + 4) * 68 + p] = fmaxf(a1.x * bf2f((ushort)v[4]) + b1.x, 0.f);
    t[(cl + 5) * 68 + p] = fmaxf(a1.y * bf2f((ushort)v[5]) + b1.y, 0.f);
    t[(cl + 6) * 68 + p] = fmaxf(a1.z * bf2f((ushort)v[6]) + b1.z, 0.f);
    t[(cl + 7) * 68 + p] = fmaxf(a1.w * bf2f((ushort)v[7]) + b1.w, 0.f);
  }
  __syncthreads();
  {
    int c = tid >> 3, x8 = (tid & 7) << 3;
    float4 r0 = *(const float4*)&t[c * 68 + x8];
    float4 r1 = *(const float4*)&t[c * 68 + x8 + 4];
    float* op = dst + ((size_t)(n * 128 + (cc << 5) + c)) * HW + (size_t)y * W + x0 + x8;
    *(float4*)op = r0;
    *(float4*)(op + 4) = r1;
  }
}

// ---------------------------------------------------------------- launch
extern "C" void kernel_launch(void* const* d_in, const int* in_sizes, int n_in,
                              void* d_out, int out_size, void* d_ws, size_t ws_size,
                              hipStream_t stream)
{
  const float* input = (const float*)d_in[0];
  const float* W1  = (const float*)d_in[1];
  const float* b1  = (const float*)d_in[2];
  const float* g1  = (const float*)d_in[3];
  const float* be1 = (const float*)d_in[4];
  const float* W2  = (const float*)d_in[5];
  const float* b2  = (const float*)d_in[6];
  const float* g2  = (const float*)d_in[7];
  const float* be2 = (const float*)d_in[8];
  const float* W3  = (const float*)d_in[9];
  const float* b3  = (const float*)d_in[10];
  const float* g3  = (const float*)d_in[11];
  const float* be3 = (const float*)d_in[12];

  char* ws = (char*)d_ws;
  ushort* h_raw    = (ushort*)(ws + 0);            // NHWC [8][65536][128]
  ushort* skip_raw = (ushort*)(ws + 134217728);    // NHWC [8][65536][128]
  ushort* dwt      = (ushort*)(ws + 268435456);    // NHWC [8][16384][512]
  ushort* in_nhwc  = (ushort*)(ws + 268435456);    // NHWC [8][65536][64] (aliased w/ dwt)
  ushort* raw3     = (ushort*)(ws + 402653184);    // NHWC [8][16384][128]
  float*  stats    = (float*)(ws + 436207616);
  float*  s1 = stats,          *q1 = stats + 4096;
  float*  s2 = stats + 8192,   *q2 = stats + 12288;
  float*  s3 = stats + 16384,  *q3 = stats + 20480;
  float*  coef = (float*)(ws + 436305920);
  float*  c1 = coef, *c2 = coef + 256, *c3 = coef + 512;
  ushort* Wp1 = (ushort*)(ws + 436308992);
  ushort* Wp2 = (ushort*)(ws + 436456448);
  ushort* Wp3 = (ushort*)(ws + 436751360);

  zero_f32<<<96, 256, 0, stream>>>(stats, 24576);
  pack_w<<<288, 256, 0, stream>>>(W1, Wp1, 64);
  pack_w<<<576, 256, 0, stream>>>(W2, Wp2, 128);
  pack_w<<<2304, 256, 0, stream>>>(W3, Wp3, 512);
  nchw2nhwc<<<dim3(1024, 8), 256, 0, stream>>>(input, in_nhwc);

  conv_mfma<0><<<dim3(4, 128, 8), 256, 0, stream>>>(in_nhwc, Wp1, b1, nullptr,
                                                    h_raw, s1, q1, 64, 256, 256);
  bn_finalize<<<1, 128, 0, stream>>>(s1, q1, g1, be1, c1, 1.f / 524288.f);

  conv_mfma<1><<<dim3(4, 128, 8), 256, 0, stream>>>(h_raw, Wp2, b2, c1,
                                                    skip_raw, s2, q2, 128, 256, 256);
  bn_finalize<<<1, 128, 0, stream>>>(s2, q2, g2, be2, c2, 1.f / 524288.f);

  skip_dwt2<<<dim3(4, 128, 32), 256, 0, stream>>>(skip_raw, c2, (float*)d_out, dwt);

  conv_mfma<0><<<dim3(2, 64, 8), 256, 0, stream>>>(dwt, Wp3, b3, nullptr,
                                                   raw3, s3, q3, 512, 128, 128);
  bn_finalize<<<1, 128, 0, stream>>>(s3, q3, g3, be3, c3, 1.f / 131072.f);

  bn_transpose_out<<<dim3(2, 128, 32), 256, 0, stream>>>(raw3, c3, (float*)d_out + 67108864, 128, 128);
}

// Round 4
// 977.724 us; speedup vs baseline: 1.0155x; 1.0155x over previous
//
#include <hip/hip_runtime.h>

typedef __attribute__((ext_vector_type(8))) short bf16x8;
typedef __attribute__((ext_vector_type(4))) short bf16x4;
typedef __attribute__((ext_vector_type(4))) float f32x4;

__device__ __forceinline__ float bf2f(ushort u) {
  union { unsigned int i; float f; } v; v.i = ((unsigned int)u) << 16; return v.f;
}
__device__ __forceinline__ ushort f2bf(float f) {
  union { float f; unsigned int i; } v; v.f = f;
  unsigned int x = v.i;
  unsigned int r = (x + 0x7fffu + ((x >> 16) & 1u)) >> 16;
  return (ushort)r;
}

// async global->LDS, 16B per lane. LDS dest must be wave-uniform base (+lane*16).
__device__ __forceinline__ void gload_lds16(const ushort* g, ushort* l) {
  __builtin_amdgcn_global_load_lds((const __attribute__((address_space(1))) void*)g,
                                   (__attribute__((address_space(3))) void*)l, 16, 0, 0);
}

// ---------------------------------------------------------------- utilities
__global__ void zero_f32(float* p, int n) {
  int i = blockIdx.x * 256 + threadIdx.x;
  if (i < n) p[i] = 0.f;
}

// Pack W[co][ci][ky][kx] (fp32) -> Wp[tap][cic][cf][lane][8] (bf16)
__global__ void pack_w(const float* __restrict__ W, ushort* __restrict__ Wp, int Cin) {
  int ncic = Cin >> 5;
  int total = 9 * ncic * 8 * 64 * 8;
  for (int idx = blockIdx.x * 256 + threadIdx.x; idx < total; idx += gridDim.x * 256) {
    int j = idx & 7;
    int l = (idx >> 3) & 63;
    int cf = (idx >> 9) & 7;
    int rest = idx >> 12;
    int cic = rest % ncic;
    int tap = rest / ncic;
    int co = cf * 16 + (l & 15);
    int ci = cic * 32 + ((l >> 4) * 8) + j;
    int ky = tap / 3, kx = tap % 3;
    Wp[idx] = f2bf(W[((co * Cin + ci) * 3 + ky) * 3 + kx]);
  }
}

// NCHW fp32 [8][64][65536] -> NHWC bf16 [8][65536][64]
__global__ __launch_bounds__(256)
void nchw2nhwc(const float* __restrict__ in, ushort* __restrict__ out) {
  const int n  = blockIdx.y;
  const int p0 = blockIdx.x << 6;
  const int tid = threadIdx.x;
  __shared__ ushort t[64 * 72];
  {
    int c  = tid >> 2;
    int pq = (tid & 3) << 4;
    const float* ip = in + (((size_t)(n * 64 + c)) << 16) + p0 + pq;
#pragma unroll
    for (int k = 0; k < 4; ++k) {
      float4 f = *(const float4*)(ip + k * 4);
      int p = pq + k * 4;
      t[(p + 0) * 72 + c] = f2bf(f.x);
      t[(p + 1) * 72 + c] = f2bf(f.y);
      t[(p + 2) * 72 + c] = f2bf(f.z);
      t[(p + 3) * 72 + c] = f2bf(f.w);
    }
  }
  __syncthreads();
#pragma unroll
  for (int k = 0; k < 2; ++k) {
    int id = k * 256 + tid;
    int cj = id & 7, p = id >> 3;
    bf16x8 v = *(const bf16x8*)&t[p * 72 + cj * 8];
    *(bf16x8*)(out + ((((size_t)n << 16) + p0 + p) << 6) + cj * 8) = v;
  }
}

__device__ __forceinline__ bf16x8 bnrelu8(bf16x8 v, const float* __restrict__ coef, int c0) {
  float4 a0 = *(const float4*)(coef + c0);
  float4 a1 = *(const float4*)(coef + c0 + 4);
  float4 b0 = *(const float4*)(coef + 128 + c0);
  float4 b1 = *(const float4*)(coef + 128 + c0 + 4);
  bf16x8 r;
  r[0] = (short)f2bf(fmaxf(a0.x * bf2f((ushort)v[0]) + b0.x, 0.f));
  r[1] = (short)f2bf(fmaxf(a0.y * bf2f((ushort)v[1]) + b0.y, 0.f));
  r[2] = (short)f2bf(fmaxf(a0.z * bf2f((ushort)v[2]) + b0.z, 0.f));
  r[3] = (short)f2bf(fmaxf(a0.w * bf2f((ushort)v[3]) + b0.w, 0.f));
  r[4] = (short)f2bf(fmaxf(a1.x * bf2f((ushort)v[4]) + b1.x, 0.f));
  r[5] = (short)f2bf(fmaxf(a1.y * bf2f((ushort)v[5]) + b1.y, 0.f));
  r[6] = (short)f2bf(fmaxf(a1.z * bf2f((ushort)v[6]) + b1.z, 0.f));
  r[7] = (short)f2bf(fmaxf(a1.w * bf2f((ushort)v[7]) + b1.w, 0.f));
  return r;
}

// in-place bn_relu on NHWC bf16 [.][128]
__global__ __launch_bounds__(256)
void bn_apply(ushort* __restrict__ p, const float* __restrict__ coef, int nvec) {
  for (int i = blockIdx.x * 256 + threadIdx.x; i < nvec; i += gridDim.x * 256) {
    int c0 = (i & 15) << 3;
    bf16x8 v = *(const bf16x8*)(p + (size_t)i * 8);
    v = bnrelu8(v, coef, c0);
    *(bf16x8*)(p + (size_t)i * 8) = v;
  }
}

// ---------------------------------------------------------------- conv core (NHWC)
// src NHWC bf16 [n][H*W][Cin] (already activated); out NHWC bf16 [n][H*W][128].
// Block: 64x * 2y * 128co; 4 waves: cg=wv>>1 (co-half), wy=wv&1 (row).
// Staging: global_load_lds dwordx4 into linear [row4][xt66][ci32] double buffer.
// Loop: STAGE(next) -> COMPUTE(cur) -> __syncthreads() (one barrier per cic).
__global__ __launch_bounds__(256)
void conv_mfma(const ushort* __restrict__ src, const ushort* __restrict__ Wp,
               const float* __restrict__ bias,
               ushort* __restrict__ out, float* __restrict__ sSum, float* __restrict__ sSsq,
               int Cin, int H, int W)
{
  const int ncic = Cin >> 5;
  const int x0 = blockIdx.x << 6;
  const int y0 = blockIdx.y << 1;
  const int n  = blockIdx.z;
  const int tid = threadIdx.x;
  const int wv = tid >> 6, l = tid & 63, l15 = l & 15, l4 = l >> 4;
  const int cg = wv >> 1;
  const int wy = wv & 1;
  const int cg4 = cg << 2;

  __shared__ __align__(16) ushort smem[2 * 8448];   // 2 x [4 rows][66 xt][32 ci]

  const size_t HW = (size_t)H * W;
  const ushort* srcn = src + (size_t)n * HW * Cin;

  // per-lane global base pointers for the 5 staging chunks (cic=0), +cic*32 elems later
  const ushort* gp[5];
  bool okf[5];
#pragma unroll
  for (int it = 0; it < 5; ++it) {
    int i = it * 256 + tid;              // chunk id, 0..1055 valid
    int cj = i & 3, p = i >> 2;
    int row = p / 66, xt = p - row * 66;
    int ry = y0 + row - 1, gx = x0 + xt - 1;
    okf[it] = (i < 1056) && ((unsigned)ry < (unsigned)H) && ((unsigned)gx < (unsigned)W);
    int cry = ry < 0 ? 0 : (ry >= H ? H - 1 : ry);
    int cgx = gx < 0 ? 0 : (gx >= W ? W - 1 : gx);
    gp[it] = srcn + ((size_t)cry * W + cgx) * Cin + (cj << 3);
  }
  const int ldsb = (wv << 6) << 3;       // wave-uniform lane-0 slot within an 'it' group

  // zero halo slots once (border blocks only; OOB slots are never DMA-written)
  if (x0 == 0 || x0 + 64 >= W || y0 == 0 || y0 + 2 >= H) {
    for (int k = tid; k < 2112; k += 256) *(bf16x8*)&smem[k << 3] = (bf16x8){};
  }
  __syncthreads();

  f32x4 acc[4][4];
#pragma unroll
  for (int f = 0; f < 4; ++f)
#pragma unroll
    for (int xf = 0; xf < 4; ++xf) acc[f][xf] = (f32x4){0.f, 0.f, 0.f, 0.f};

  auto STAGE = [&](int bufsel, int cic) {
    ushort* base = smem + bufsel * 8448;
    const size_t coff = (size_t)cic << 5;
#pragma unroll
    for (int it = 0; it < 5; ++it) {
      if (okf[it])
        gload_lds16(gp[it] + coff, base + (it << 11) + ldsb);
    }
  };

  auto COMPUTE = [&](const ushort* buf, int cic) {
    const ushort* wp = Wp + (((size_t)cic * 8) + cg4) * 512 + ((size_t)l << 3);
    const size_t tstride = (size_t)ncic * 4096;
    const ushort* lrow = buf + (size_t)l15 * 32 + (l4 << 3);
#pragma unroll
    for (int tap = 0; tap < 9; ++tap) {
      const int ky = tap / 3, kx = tap % 3;
      bf16x8 a[4], b[4];
#pragma unroll
      for (int f = 0; f < 4; ++f)
        a[f] = *(const bf16x8*)(wp + (size_t)tap * tstride + (f << 9));
#pragma unroll
      for (int xf = 0; xf < 4; ++xf)
        b[xf] = *(const bf16x8*)(lrow + (((wy + ky) * 66 + (xf << 4) + kx) << 5));
#pragma unroll
      for (int f = 0; f < 4; ++f)
#pragma unroll
        for (int xf = 0; xf < 4; ++xf)
          acc[f][xf] = __builtin_amdgcn_mfma_f32_16x16x32_bf16(a[f], b[xf], acc[f][xf], 0, 0, 0);
    }
  };

  STAGE(0, 0);
  __syncthreads();

  int cur = 0;
  for (int cic = 0; cic < ncic; ++cic) {
    if (cic + 1 < ncic) STAGE(cur ^ 1, cic + 1);
    COMPUTE(smem + cur * 8448, cic);
    __syncthreads();
    cur ^= 1;
  }

  // ------------- epilogue: bias, stats, NHWC store via LDS transpose
  float smv[4][4] = {{0.f}}, sqv[4][4] = {{0.f}};
  ushort* eps = smem;   // [x64][co 136]
  for (int yr = 0; yr < 2; ++yr) {
    __syncthreads();
    if (wy == yr) {
#pragma unroll
      for (int f = 0; f < 4; ++f) {
        const int col = (cg << 6) + (f << 4) + (l4 << 2);
        float4 bv = *(const float4*)(bias + col);
#pragma unroll
        for (int xf = 0; xf < 4; ++xf) {
          float v0 = acc[f][xf][0] + bv.x;
          float v1 = acc[f][xf][1] + bv.y;
          float v2 = acc[f][xf][2] + bv.z;
          float v3 = acc[f][xf][3] + bv.w;
          smv[f][0] += v0; sqv[f][0] += v0 * v0;
          smv[f][1] += v1; sqv[f][1] += v1 * v1;
          smv[f][2] += v2; sqv[f][2] += v2 * v2;
          smv[f][3] += v3; sqv[f][3] += v3 * v3;
          bf16x4 u;
          u[0] = (short)f2bf(v0); u[1] = (short)f2bf(v1);
          u[2] = (short)f2bf(v2); u[3] = (short)f2bf(v3);
          *(bf16x4*)&eps[((xf << 4) + l15) * 136 + col] = u;
        }
      }
    }
    __syncthreads();
    {
      const int xx = tid >> 2, c0 = (tid & 3) << 5;
      ushort* op = out + ((size_t)n * HW + (size_t)(y0 + yr) * W + x0 + xx) * 128 + c0;
#pragma unroll
      for (int k = 0; k < 4; ++k)
        *(bf16x8*)(op + (k << 3)) = *(const bf16x8*)&eps[xx * 136 + c0 + (k << 3)];
    }
  }

  const int rep = (int)((blockIdx.z * gridDim.y + blockIdx.y) * gridDim.x + blockIdx.x) & 31;
#pragma unroll
  for (int f = 0; f < 4; ++f)
#pragma unroll
    for (int j = 0; j < 4; ++j) {
      float s = smv[f][j], q = sqv[f][j];
#pragma unroll
      for (int o = 1; o < 16; o <<= 1) { s += __shfl_xor(s, o); q += __shfl_xor(q, o); }
      if (l15 == 0) {
        int co = (cg << 6) + (f << 4) + (l4 << 2) + j;
        atomicAdd(&sSum[rep * 128 + co], s);
        atomicAdd(&sSsq[rep * 128 + co], q);
      }
    }
}

// ---------------------------------------------------------------- BN finalize
__global__ void bn_finalize(const float* __restrict__ sSum, const float* __restrict__ sSsq,
                            const float* __restrict__ g, const float* __restrict__ be,
                            float* __restrict__ coef, float invN)
{
  int c = threadIdx.x;  // 128
  float S = 0.f, Q = 0.f;
  for (int r = 0; r < 32; ++r) { S += sSum[r * 128 + c]; Q += sSsq[r * 128 + c]; }
  float m = S * invN;
  float v = Q * invN - m * m;
  float a = g[c] / sqrtf(v + 1e-5f);
  coef[c] = a;
  coef[128 + c] = be[c] - m * a;
}

// ---------------------------------------------------------------- fused bn_relu + skip out (NCHW fp32) + DWT (NHWC bf16)
__global__ __launch_bounds__(256)
void skip_dwt2(const ushort* __restrict__ skipRaw, const float* __restrict__ coef,
               float* __restrict__ outSkip, ushort* __restrict__ dwt)
{
  const int x0 = blockIdx.x << 6;
  const int oy = blockIdx.y;
  const int n  = blockIdx.z >> 2;
  const int ct = blockIdx.z & 3;
  const int y0 = oy << 1;
  const int tid = threadIdx.x;
  __shared__ float t32[32 * 2 * 68];

#pragma unroll
  for (int it = 0; it < 2; ++it) {
    int i = it * 256 + tid;
    int cj = i & 3, x = (i >> 2) & 63, r = i >> 8;
    int c0 = (ct << 5) + (cj << 3);
    bf16x8 v = *(const bf16x8*)(skipRaw + (((size_t)n << 16) + (size_t)(y0 + r) * 256 + x0 + x) * 128 + c0);
    float4 a0 = *(const float4*)(coef + c0);
    float4 a1 = *(const float4*)(coef + c0 + 4);
    float4 b0 = *(const float4*)(coef + 128 + c0);
    float4 b1 = *(const float4*)(coef + 128 + c0 + 4);
    float av[8] = {a0.x, a0.y, a0.z, a0.w, a1.x, a1.y, a1.z, a1.w};
    float bv[8] = {b0.x, b0.y, b0.z, b0.w, b1.x, b1.y, b1.z, b1.w};
    int cl = cj << 3;
#pragma unroll
    for (int k = 0; k < 8; ++k)
      t32[((cl + k) * 2 + r) * 68 + x] = fmaxf(av[k] * bf2f((ushort)v[k]) + bv[k], 0.f);
  }
  __syncthreads();

  {
    int c = tid >> 3, x8 = (tid & 7) << 3;
    float* op = outSkip + (((size_t)(n * 128 + (ct << 5) + c)) << 16) + (size_t)y0 * 256 + x0 + x8;
#pragma unroll
    for (int r = 0; r < 2; ++r) {
      float4 r0 = *(const float4*)&t32[(c * 2 + r) * 68 + x8];
      float4 r1 = *(const float4*)&t32[(c * 2 + r) * 68 + x8 + 4];
      *(float4*)(op + (size_t)r * 256) = r0;
      *(float4*)(op + (size_t)r * 256 + 4) = r1;
    }
  }

  if (tid < 128) {
    int cj = tid & 3, ox = tid >> 2;
    int cl = cj << 3;
    bf16x8 oA, oH, oV, oD;
#pragma unroll
    for (int k = 0; k < 8; ++k) {
      int c = cl + k;
      float p00 = t32[(c * 2 + 0) * 68 + 2 * ox];
      float p01 = t32[(c * 2 + 0) * 68 + 2 * ox + 1];
      float p10 = t32[(c * 2 + 1) * 68 + 2 * ox];
      float p11 = t32[(c * 2 + 1) * 68 + 2 * ox + 1];
      oA[k] = (short)f2bf((p00 + p01 + p10 + p11) * 0.5f);
      oH[k] = (short)f2bf((p00 + p01 - p10 - p11) * 0.5f);
      oV[k] = (short)f2bf((p00 - p01 + p10 - p11) * 0.5f);
      oD[k] = (short)f2bf((p00 - p01 - p10 + p11) * 0.5f);
    }
    size_t db = ((size_t)n * 16384 + (size_t)oy * 128 + (x0 >> 1) + ox) * 512 + (ct << 5) + cl;
    *(bf16x8*)(dwt + db)       = oA;
    *(bf16x8*)(dwt + db + 128) = oH;
    *(bf16x8*)(dwt + db + 256) = oV;
    *(bf16x8*)(dwt + db + 384) = oD;
  }
}

// ---------------------------------------------------------------- bn_relu + NHWC->NCHW fp32 out
__global__ __launch_bounds__(256)
void bn_transpose_out(const ushort* __restrict__ src, const float* __restrict__ coef,
                      float* __restrict__ dst, int H, int W)
{
  const int n  = blockIdx.z >> 2;
  const int cc = blockIdx.z & 3;
  const int x0 = blockIdx.x << 6;
  const int y  = blockIdx.y;
  const int tid = threadIdx.x;
  __shared__ float t[32 * 68];
  const size_t HW = (size_t)H * W;
  {
    int p = tid >> 2, cj = tid & 3;
    int c0 = (cc << 5) + (cj << 3);
    bf16x8 v = *(const bf16x8*)(src + ((size_t)n * HW + (size_t)y * W + x0 + p) * 128 + c0);
    float4 a0 = *(const float4*)(coef + c0);
    float4 a1 = *(const float4*)(coef + c0 + 4);
    float4 b0 = *(const float4*)(coef + 128 + c0);
    float4 b1 = *(const float4*)(coef + 128 + c0 + 4);
    int cl = cj << 3;
    t[(cl + 0) * 68 + p] = fmaxf(a0.x * bf2f((ushort)v[0]) + b0.x, 0.f);
    t[(cl + 1) * 68 + p] = fmaxf(a0.y * bf2f((ushort)v[1]) + b0.y, 0.f);
    t[(cl + 2) * 68 + p] = fmaxf(a0.z * bf2f((ushort)v[2]) + b0.z, 0.f);
    t[(cl + 3) * 68 + p] = fmaxf(a0.w * bf2f((ushort)v[3]) + b0.w, 0.f);
    t[(cl + 4) * 68 + p] = fmaxf(a1.x * bf2f((ushort)v[4]) + b1.x, 0.f);
    t[(cl + 5) * 68 + p] = fmaxf(a1.y * bf2f((ushort)v[5]) + b1.y, 0.f);
    t[(cl + 6) * 68 + p] = fmaxf(a1.z * bf2f((ushort)v[6]) + b1.z, 0.f);
    t[(cl + 7) * 68 + p] = fmaxf(a1.w * bf2f((ushort)v[7]) + b1.w, 0.f);
  }
  __syncthreads();
  {
    int c = tid >> 3, x8 = (tid & 7) << 3;
    float4 r0 = *(const float4*)&t[c * 68 + x8];
    float4 r1 = *(const float4*)&t[c * 68 + x8 + 4];
    float* op = dst + ((size_t)(n * 128 + (cc << 5) + c)) * HW + (size_t)y * W + x0 + x8;
    *(float4*)op = r0;
    *(float4*)(op + 4) = r1;
  }
}

// ---------------------------------------------------------------- launch
extern "C" void kernel_launch(void* const* d_in, const int* in_sizes, int n_in,
                              void* d_out, int out_size, void* d_ws, size_t ws_size,
                              hipStream_t stream)
{
  const float* input = (const float*)d_in[0];
  const float* W1  = (const float*)d_in[1];
  const float* b1  = (const float*)d_in[2];
  const float* g1  = (const float*)d_in[3];
  const float* be1 = (const float*)d_in[4];
  const float* W2  = (const float*)d_in[5];
  const float* b2  = (const float*)d_in[6];
  const float* g2  = (const float*)d_in[7];
  const float* be2 = (const float*)d_in[8];
  const float* W3  = (const float*)d_in[9];
  const float* b3  = (const float*)d_in[10];
  const float* g3  = (const float*)d_in[11];
  const float* be3 = (const float*)d_in[12];

  char* ws = (char*)d_ws;
  ushort* h_raw    = (ushort*)(ws + 0);            // NHWC [8][65536][128]
  ushort* skip_raw = (ushort*)(ws + 134217728);    // NHWC [8][65536][128]
  ushort* dwt      = (ushort*)(ws + 268435456);    // NHWC [8][16384][512]
  ushort* in_nhwc  = (ushort*)(ws + 268435456);    // NHWC [8][65536][64] (aliased w/ dwt)
  ushort* raw3     = (ushort*)(ws + 402653184);    // NHWC [8][16384][128]
  float*  stats    = (float*)(ws + 436207616);
  float*  s1 = stats,          *q1 = stats + 4096;
  float*  s2 = stats + 8192,   *q2 = stats + 12288;
  float*  s3 = stats + 16384,  *q3 = stats + 20480;
  float*  coef = (float*)(ws + 436305920);
  float*  c1 = coef, *c2 = coef + 256, *c3 = coef + 512;
  ushort* Wp1 = (ushort*)(ws + 436308992);
  ushort* Wp2 = (ushort*)(ws + 436456448);
  ushort* Wp3 = (ushort*)(ws + 436751360);

  zero_f32<<<96, 256, 0, stream>>>(stats, 24576);
  pack_w<<<288, 256, 0, stream>>>(W1, Wp1, 64);
  pack_w<<<576, 256, 0, stream>>>(W2, Wp2, 128);
  pack_w<<<2304, 256, 0, stream>>>(W3, Wp3, 512);
  nchw2nhwc<<<dim3(1024, 8), 256, 0, stream>>>(input, in_nhwc);

  conv_mfma<<<dim3(4, 128, 8), 256, 0, stream>>>(in_nhwc, Wp1, b1,
                                                 h_raw, s1, q1, 64, 256, 256);
  bn_finalize<<<1, 128, 0, stream>>>(s1, q1, g1, be1, c1, 1.f / 524288.f);

  bn_apply<<<2048, 256, 0, stream>>>(h_raw, c1, 8388608);

  conv_mfma<<<dim3(4, 128, 8), 256, 0, stream>>>(h_raw, Wp2, b2,
                                                 skip_raw, s2, q2, 128, 256, 256);
  bn_finalize<<<1, 128, 0, stream>>>(s2, q2, g2, be2, c2, 1.f / 524288.f);

  skip_dwt2<<<dim3(4, 128, 32), 256, 0, stream>>>(skip_raw, c2, (float*)d_out, dwt);

  conv_mfma<<<dim3(2, 64, 8), 256, 0, stream>>>(dwt, Wp3, b3,
                                                raw3, s3, q3, 512, 128, 128);
  bn_finalize<<<1, 128, 0, stream>>>(s3, q3, g3, be3, c3, 1.f / 131072.f);

  bn_transpose_out<<<dim3(2, 128, 32), 256, 0, stream>>>(raw3, c3, (float*)d_out + 67108864, 128, 128);
}

// Round 5
// 744.480 us; speedup vs baseline: 1.3336x; 1.3133x over previous
//
#include <hip/hip_runtime.h>

typedef __attribute__((ext_vector_type(8))) short bf16x8;
typedef __attribute__((ext_vector_type(4))) short bf16x4;
typedef __attribute__((ext_vector_type(4))) float f32x4;

__device__ __forceinline__ float bf2f(ushort u) {
  union { unsigned int i; float f; } v; v.i = ((unsigned int)u) << 16; return v.f;
}
__device__ __forceinline__ ushort f2bf(float f) {
  union { float f; unsigned int i; } v; v.f = f;
  unsigned int x = v.i;
  unsigned int r = (x + 0x7fffu + ((x >> 16) & 1u)) >> 16;
  return (ushort)r;
}

// ---------------------------------------------------------------- utilities
__global__ void zero_f32(float* p, int n) {
  int i = blockIdx.x * 256 + threadIdx.x;
  if (i < n) p[i] = 0.f;
}

// Pack W[co][ci][ky][kx] (fp32) -> Wp[tap][cic][cf][lane][8] (bf16)
__global__ void pack_w(const float* __restrict__ W, ushort* __restrict__ Wp, int Cin) {
  int ncic = Cin >> 5;
  int total = 9 * ncic * 8 * 64 * 8;
  for (int idx = blockIdx.x * 256 + threadIdx.x; idx < total; idx += gridDim.x * 256) {
    int j = idx & 7;
    int l = (idx >> 3) & 63;
    int cf = (idx >> 9) & 7;
    int rest = idx >> 12;
    int cic = rest % ncic;
    int tap = rest / ncic;
    int co = cf * 16 + (l & 15);
    int ci = cic * 32 + ((l >> 4) * 8) + j;
    int ky = tap / 3, kx = tap % 3;
    Wp[idx] = f2bf(W[((co * Cin + ci) * 3 + ky) * 3 + kx]);
  }
}

// NCHW fp32 [8][64][65536] -> NHWC bf16 [8][65536][64]
__global__ __launch_bounds__(256)
void nchw2nhwc(const float* __restrict__ in, ushort* __restrict__ out) {
  const int n  = blockIdx.y;
  const int p0 = blockIdx.x << 6;
  const int tid = threadIdx.x;
  __shared__ ushort t[64 * 72];
  {
    int c  = tid >> 2;
    int pq = (tid & 3) << 4;
    const float* ip = in + (((size_t)(n * 64 + c)) << 16) + p0 + pq;
#pragma unroll
    for (int k = 0; k < 4; ++k) {
      float4 f = *(const float4*)(ip + k * 4);
      int p = pq + k * 4;
      t[(p + 0) * 72 + c] = f2bf(f.x);
      t[(p + 1) * 72 + c] = f2bf(f.y);
      t[(p + 2) * 72 + c] = f2bf(f.z);
      t[(p + 3) * 72 + c] = f2bf(f.w);
    }
  }
  __syncthreads();
#pragma unroll
  for (int k = 0; k < 2; ++k) {
    int id = k * 256 + tid;
    int cj = id & 7, p = id >> 3;
    bf16x8 v = *(const bf16x8*)&t[p * 72 + cj * 8];
    *(bf16x8*)(out + ((((size_t)n << 16) + p0 + p) << 6) + cj * 8) = v;
  }
}

__device__ __forceinline__ bf16x8 bnrelu8(bf16x8 v, const float* __restrict__ coef, int c0) {
  float4 a0 = *(const float4*)(coef + c0);
  float4 a1 = *(const float4*)(coef + c0 + 4);
  float4 b0 = *(const float4*)(coef + 128 + c0);
  float4 b1 = *(const float4*)(coef + 128 + c0 + 4);
  bf16x8 r;
  r[0] = (short)f2bf(fmaxf(a0.x * bf2f((ushort)v[0]) + b0.x, 0.f));
  r[1] = (short)f2bf(fmaxf(a0.y * bf2f((ushort)v[1]) + b0.y, 0.f));
  r[2] = (short)f2bf(fmaxf(a0.z * bf2f((ushort)v[2]) + b0.z, 0.f));
  r[3] = (short)f2bf(fmaxf(a0.w * bf2f((ushort)v[3]) + b0.w, 0.f));
  r[4] = (short)f2bf(fmaxf(a1.x * bf2f((ushort)v[4]) + b1.x, 0.f));
  r[5] = (short)f2bf(fmaxf(a1.y * bf2f((ushort)v[5]) + b1.y, 0.f));
  r[6] = (short)f2bf(fmaxf(a1.z * bf2f((ushort)v[6]) + b1.z, 0.f));
  r[7] = (short)f2bf(fmaxf(a1.w * bf2f((ushort)v[7]) + b1.w, 0.f));
  return r;
}

// ---------------------------------------------------------------- conv core (NHWC)
// src NHWC bf16 [n][H*W][Cin]; out NHWC bf16 [n][H*W][128].
// Block: 512 threads = 8 waves = 4 co-quarters (cg, 2 cf each) x 2 rows (wy).
// Per wave: acc 2cf x 4xf = 32 AGPR; VGPR target <= 96 total -> 4 waves/SIMD.
// Staging: T14 split (global->reg before COMPUTE, reg->LDS after), fused bnrelu (MODE 1).
template<int MODE>
__global__ __launch_bounds__(512, 4)
void conv_mfma(const ushort* __restrict__ src, const ushort* __restrict__ Wp,
               const float* __restrict__ bias, const float* __restrict__ coef,
               ushort* __restrict__ out, float* __restrict__ sSum, float* __restrict__ sSsq,
               int Cin, int H, int W)
{
  const int ncic = Cin >> 5;
  const int x0 = blockIdx.x << 6;
  const int y0 = blockIdx.y << 1;
  const int n  = blockIdx.z;
  const int tid = threadIdx.x;
  const int wv = tid >> 6, l = tid & 63, l15 = l & 15, l4 = l >> 4;
  const int cg = wv >> 1;      // co quarter 0..3
  const int wy = wv & 1;       // output row

  __shared__ __align__(16) ushort smem[2 * 8448];   // 2 x [4 rows][66 xt][32 ci]

  const size_t HW = (size_t)H * W;
  const ushort* srcn = src + (size_t)n * HW * Cin;

  // chunk geometry: i = it*512 + tid (i < 1056); cj=i&3, p=i>>2, row=p/66, xt=p%66
  int off[3];
#pragma unroll
  for (int it = 0; it < 3; ++it) {
    int i = it * 512 + tid;
    int cj = i & 3, p = i >> 2;
    int row = p / 66, xt = p - row * 66;
    int ry = y0 + row - 1, gx = x0 + xt - 1;
    bool ok = (i < 1056) && ((unsigned)ry < (unsigned)H) && ((unsigned)gx < (unsigned)W);
    off[it] = ok ? (int)((ry * W + gx) * Cin + (cj << 3)) : -1;
  }

  f32x4 acc[2][4];
#pragma unroll
  for (int f = 0; f < 2; ++f)
#pragma unroll
    for (int xf = 0; xf < 4; ++xf) acc[f][xf] = (f32x4){0.f, 0.f, 0.f, 0.f};

  bf16x8 st[3];

  auto LOADREG = [&](int cic) {
#pragma unroll
    for (int it = 0; it < 3; ++it) {
      bf16x8 v = {};
      if (off[it] >= 0) v = *(const bf16x8*)(srcn + off[it] + (cic << 5));
      st[it] = v;
    }
  };

  auto WRITE = [&](ushort* buf, int cic) {
#pragma unroll
    for (int it = 0; it < 3; ++it) {
      if (it < 2 || tid < 32) {
        int i = it * 512 + tid;
        bf16x8 v = st[it];
        if (MODE == 1) {
          if (off[it] >= 0) v = bnrelu8(v, coef, (cic << 5) + ((i & 3) << 3));
        }
        *(bf16x8*)(buf + i * 8) = v;
      }
    }
  };

  auto COMPUTE = [&](const ushort* buf, int cic) {
    const ushort* wp = Wp + ((size_t)cic * 8 + (cg << 1)) * 512 + ((size_t)l << 3);
    const size_t tstride = (size_t)ncic * 4096;
    const ushort* lrow = buf + (size_t)l15 * 32 + (l4 << 3);
#pragma unroll
    for (int tap = 0; tap < 9; ++tap) {
      const int ky = tap / 3, kx = tap % 3;
      bf16x8 a0 = *(const bf16x8*)(wp + (size_t)tap * tstride);
      bf16x8 a1 = *(const bf16x8*)(wp + (size_t)tap * tstride + 512);
      bf16x8 b[4];
#pragma unroll
      for (int xf = 0; xf < 4; ++xf)
        b[xf] = *(const bf16x8*)(lrow + (((wy + ky) * 66 + (xf << 4) + kx) << 5));
#pragma unroll
      for (int xf = 0; xf < 4; ++xf) {
        acc[0][xf] = __builtin_amdgcn_mfma_f32_16x16x32_bf16(a0, b[xf], acc[0][xf], 0, 0, 0);
        acc[1][xf] = __builtin_amdgcn_mfma_f32_16x16x32_bf16(a1, b[xf], acc[1][xf], 0, 0, 0);
      }
    }
  };

  LOADREG(0);
  WRITE(smem, 0);
  __syncthreads();

  int cur = 0;
  for (int cic = 0; cic < ncic; ++cic) {
    if (cic + 1 < ncic) LOADREG(cic + 1);
    COMPUTE(smem + cur * 8448, cic);
    if (cic + 1 < ncic) WRITE(smem + (cur ^ 1) * 8448, cic + 1);
    __syncthreads();
    cur ^= 1;
  }

  // ------------- epilogue: bias, stats, NHWC store via LDS transpose
  float smv[2][4] = {{0.f}}, sqv[2][4] = {{0.f}};
  ushort* eps = smem;   // [x64][co 136]
  for (int yr = 0; yr < 2; ++yr) {
    __syncthreads();
    if (wy == yr) {
#pragma unroll
      for (int f = 0; f < 2; ++f) {
        const int col = (cg << 5) + (f << 4) + (l4 << 2);
        float4 bv = *(const float4*)(bias + col);
#pragma unroll
        for (int xf = 0; xf < 4; ++xf) {
          float v0 = acc[f][xf][0] + bv.x;
          float v1 = acc[f][xf][1] + bv.y;
          float v2 = acc[f][xf][2] + bv.z;
          float v3 = acc[f][xf][3] + bv.w;
          smv[f][0] += v0; sqv[f][0] += v0 * v0;
          smv[f][1] += v1; sqv[f][1] += v1 * v1;
          smv[f][2] += v2; sqv[f][2] += v2 * v2;
          smv[f][3] += v3; sqv[f][3] += v3 * v3;
          bf16x4 u;
          u[0] = (short)f2bf(v0); u[1] = (short)f2bf(v1);
          u[2] = (short)f2bf(v2); u[3] = (short)f2bf(v3);
          *(bf16x4*)&eps[((xf << 4) + l15) * 136 + col] = u;
        }
      }
    }
    __syncthreads();
    {
      const int xx = tid >> 3, c0 = (tid & 7) << 4;
      ushort* op = out + ((size_t)n * HW + (size_t)(y0 + yr) * W + x0 + xx) * 128 + c0;
      *(bf16x8*)op       = *(const bf16x8*)&eps[xx * 136 + c0];
      *(bf16x8*)(op + 8) = *(const bf16x8*)&eps[xx * 136 + c0 + 8];
    }
  }

  const int rep = (int)((blockIdx.z * gridDim.y + blockIdx.y) * gridDim.x + blockIdx.x) & 31;
#pragma unroll
  for (int f = 0; f < 2; ++f)
#pragma unroll
    for (int j = 0; j < 4; ++j) {
      float s = smv[f][j], q = sqv[f][j];
#pragma unroll
      for (int o = 1; o < 16; o <<= 1) { s += __shfl_xor(s, o); q += __shfl_xor(q, o); }
      if (l15 == 0) {
        int co = (cg << 5) + (f << 4) + (l4 << 2) + j;
        atomicAdd(&sSum[rep * 128 + co], s);
        atomicAdd(&sSsq[rep * 128 + co], q);
      }
    }
}

// ---------------------------------------------------------------- BN finalize
__global__ void bn_finalize(const float* __restrict__ sSum, const float* __restrict__ sSsq,
                            const float* __restrict__ g, const float* __restrict__ be,
                            float* __restrict__ coef, float invN)
{
  int c = threadIdx.x;  // 128
  float S = 0.f, Q = 0.f;
  for (int r = 0; r < 32; ++r) { S += sSum[r * 128 + c]; Q += sSsq[r * 128 + c]; }
  float m = S * invN;
  float v = Q * invN - m * m;
  float a = g[c] / sqrtf(v + 1e-5f);
  coef[c] = a;
  coef[128 + c] = be[c] - m * a;
}

// ---------------------------------------------------------------- fused bn_relu + skip out (NCHW fp32) + DWT (NHWC bf16)
__global__ __launch_bounds__(256)
void skip_dwt2(const ushort* __restrict__ skipRaw, const float* __restrict__ coef,
               float* __restrict__ outSkip, ushort* __restrict__ dwt)
{
  const int x0 = blockIdx.x << 6;
  const int oy = blockIdx.y;
  const int n  = blockIdx.z >> 2;
  const int ct = blockIdx.z & 3;
  const int y0 = oy << 1;
  const int tid = threadIdx.x;
  __shared__ float t32[32 * 2 * 68];

#pragma unroll
  for (int it = 0; it < 2; ++it) {
    int i = it * 256 + tid;
    int cj = i & 3, x = (i >> 2) & 63, r = i >> 8;
    int c0 = (ct << 5) + (cj << 3);
    bf16x8 v = *(const bf16x8*)(skipRaw + (((size_t)n << 16) + (size_t)(y0 + r) * 256 + x0 + x) * 128 + c0);
    float4 a0 = *(const float4*)(coef + c0);
    float4 a1 = *(const float4*)(coef + c0 + 4);
    float4 b0 = *(const float4*)(coef + 128 + c0);
    float4 b1 = *(const float4*)(coef + 128 + c0 + 4);
    float av[8] = {a0.x, a0.y, a0.z, a0.w, a1.x, a1.y, a1.z, a1.w};
    float bv[8] = {b0.x, b0.y, b0.z, b0.w, b1.x, b1.y, b1.z, b1.w};
    int cl = cj << 3;
#pragma unroll
    for (int k = 0; k < 8; ++k)
      t32[((cl + k) * 2 + r) * 68 + x] = fmaxf(av[k] * bf2f((ushort)v[k]) + bv[k], 0.f);
  }
  __syncthreads();

  {
    int c = tid >> 3, x8 = (tid & 7) << 3;
    float* op = outSkip + (((size_t)(n * 128 + (ct << 5) + c)) << 16) + (size_t)y0 * 256 + x0 + x8;
#pragma unroll
    for (int r = 0; r < 2; ++r) {
      float4 r0 = *(const float4*)&t32[(c * 2 + r) * 68 + x8];
      float4 r1 = *(const float4*)&t32[(c * 2 + r) * 68 + x8 + 4];
      *(float4*)(op + (size_t)r * 256) = r0;
      *(float4*)(op + (size_t)r * 256 + 4) = r1;
    }
  }

  if (tid < 128) {
    int cj = tid & 3, ox = tid >> 2;
    int cl = cj << 3;
    bf16x8 oA, oH, oV, oD;
#pragma unroll
    for (int k = 0; k < 8; ++k) {
      int c = cl + k;
      float p00 = t32[(c * 2 + 0) * 68 + 2 * ox];
      float p01 = t32[(c * 2 + 0) * 68 + 2 * ox + 1];
      float p10 = t32[(c * 2 + 1) * 68 + 2 * ox];
      float p11 = t32[(c * 2 + 1) * 68 + 2 * ox + 1];
      oA[k] = (short)f2bf((p00 + p01 + p10 + p11) * 0.5f);
      oH[k] = (short)f2bf((p00 + p01 - p10 - p11) * 0.5f);
      oV[k] = (short)f2bf((p00 - p01 + p10 - p11) * 0.5f);
      oD[k] = (short)f2bf((p00 - p01 - p10 + p11) * 0.5f);
    }
    size_t db = ((size_t)n * 16384 + (size_t)oy * 128 + (x0 >> 1) + ox) * 512 + (ct << 5) + cl;
    *(bf16x8*)(dwt + db)       = oA;
    *(bf16x8*)(dwt + db + 128) = oH;
    *(bf16x8*)(dwt + db + 256) = oV;
    *(bf16x8*)(dwt + db + 384) = oD;
  }
}

// ---------------------------------------------------------------- bn_relu + NHWC->NCHW fp32 out
__global__ __launch_bounds__(256)
void bn_transpose_out(const ushort* __restrict__ src, const float* __restrict__ coef,
                      float* __restrict__ dst, int H, int W)
{
  const int n  = blockIdx.z >> 2;
  const int cc = blockIdx.z & 3;
  const int x0 = blockIdx.x << 6;
  const int y  = blockIdx.y;
  const int tid = threadIdx.x;
  __shared__ float t[32 * 68];
  const size_t HW = (size_t)H * W;
  {
    int p = tid >> 2, cj = tid & 3;
    int c0 = (cc << 5) + (cj << 3);
    bf16x8 v = *(const bf16x8*)(src + ((size_t)n * HW + (size_t)y * W + x0 + p) * 128 + c0);
    float4 a0 = *(const float4*)(coef + c0);
    float4 a1 = *(const float4*)(coef + c0 + 4);
    float4 b0 = *(const float4*)(coef + 128 + c0);
    float4 b1 = *(const float4*)(coef + 128 + c0 + 4);
    int cl = cj << 3;
    t[(cl + 0) * 68 + p] = fmaxf(a0.x * bf2f((ushort)v[0]) + b0.x, 0.f);
    t[(cl + 1) * 68 + p] = fmaxf(a0.y * bf2f((ushort)v[1]) + b0.y, 0.f);
    t[(cl + 2) * 68 + p] = fmaxf(a0.z * bf2f((ushort)v[2]) + b0.z, 0.f);
    t[(cl + 3) * 68 + p] = fmaxf(a0.w * bf2f((ushort)v[3]) + b0.w, 0.f);
    t[(cl + 4) * 68 + p] = fmaxf(a1.x * bf2f((ushort)v[4]) + b1.x, 0.f);
    t[(cl + 5) * 68 + p] = fmaxf(a1.y * bf2f((ushort)v[5]) + b1.y, 0.f);
    t[(cl + 6) * 68 + p] = fmaxf(a1.z * bf2f((ushort)v[6]) + b1.z, 0.f);
    t[(cl + 7) * 68 + p] = fmaxf(a1.w * bf2f((ushort)v[7]) + b1.w, 0.f);
  }
  __syncthreads();
  {
    int c = tid >> 3, x8 = (tid & 7) << 3;
    float4 r0 = *(const float4*)&t[c * 68 + x8];
    float4 r1 = *(const float4*)&t[c * 68 + x8 + 4];
    float* op = dst + ((size_t)(n * 128 + (cc << 5) + c)) * HW + (size_t)y * W + x0 + x8;
    *(float4*)op = r0;
    *(float4*)(op + 4) = r1;
  }
}

// ---------------------------------------------------------------- launch
extern "C" void kernel_launch(void* const* d_in, const int* in_sizes, int n_in,
                              void* d_out, int out_size, void* d_ws, size_t ws_size,
                              hipStream_t stream)
{
  const float* input = (const float*)d_in[0];
  const float* W1  = (const float*)d_in[1];
  const float* b1  = (const float*)d_in[2];
  const float* g1  = (const float*)d_in[3];
  const float* be1 = (const float*)d_in[4];
  const float* W2  = (const float*)d_in[5];
  const float* b2  = (const float*)d_in[6];
  const float* g2  = (const float*)d_in[7];
  const float* be2 = (const float*)d_in[8];
  const float* W3  = (const float*)d_in[9];
  const float* b3  = (const float*)d_in[10];
  const float* g3  = (const float*)d_in[11];
  const float* be3 = (const float*)d_in[12];

  char* ws = (char*)d_ws;
  ushort* h_raw    = (ushort*)(ws + 0);            // NHWC [8][65536][128]
  ushort* skip_raw = (ushort*)(ws + 134217728);    // NHWC [8][65536][128]
  ushort* dwt      = (ushort*)(ws + 268435456);    // NHWC [8][16384][512]
  ushort* in_nhwc  = (ushort*)(ws + 268435456);    // NHWC [8][65536][64] (aliased w/ dwt)
  ushort* raw3     = (ushort*)(ws + 402653184);    // NHWC [8][16384][128]
  float*  stats    = (float*)(ws + 436207616);
  float*  s1 = stats,          *q1 = stats + 4096;
  float*  s2 = stats + 8192,   *q2 = stats + 12288;
  float*  s3 = stats + 16384,  *q3 = stats + 20480;
  float*  coef = (float*)(ws + 436305920);
  float*  c1 = coef, *c2 = coef + 256, *c3 = coef + 512;
  ushort* Wp1 = (ushort*)(ws + 436308992);
  ushort* Wp2 = (ushort*)(ws + 436456448);
  ushort* Wp3 = (ushort*)(ws + 436751360);

  zero_f32<<<96, 256, 0, stream>>>(stats, 24576);
  pack_w<<<288, 256, 0, stream>>>(W1, Wp1, 64);
  pack_w<<<576, 256, 0, stream>>>(W2, Wp2, 128);
  pack_w<<<2304, 256, 0, stream>>>(W3, Wp3, 512);
  nchw2nhwc<<<dim3(1024, 8), 256, 0, stream>>>(input, in_nhwc);

  conv_mfma<0><<<dim3(4, 128, 8), 512, 0, stream>>>(in_nhwc, Wp1, b1, nullptr,
                                                    h_raw, s1, q1, 64, 256, 256);
  bn_finalize<<<1, 128, 0, stream>>>(s1, q1, g1, be1, c1, 1.f / 524288.f);

  conv_mfma<1><<<dim3(4, 128, 8), 512, 0, stream>>>(h_raw, Wp2, b2, c1,
                                                    skip_raw, s2, q2, 128, 256, 256);
  bn_finalize<<<1, 128, 0, stream>>>(s2, q2, g2, be2, c2, 1.f / 524288.f);

  skip_dwt2<<<dim3(4, 128, 32), 256, 0, stream>>>(skip_raw, c2, (float*)d_out, dwt);

  conv_mfma<0><<<dim3(2, 64, 8), 512, 0, stream>>>(dwt, Wp3, b3, nullptr,
                                                   raw3, s3, q3, 512, 128, 128);
  bn_finalize<<<1, 128, 0, stream>>>(s3, q3, g3, be3, c3, 1.f / 131072.f);

  bn_transpose_out<<<dim3(2, 128, 32), 256, 0, stream>>>(raw3, c3, (float*)d_out + 67108864, 128, 128);
}

// Round 6
// 716.214 us; speedup vs baseline: 1.3863x; 1.0395x over previous
//
#include <hip/hip_runtime.h>

typedef __attribute__((ext_vector_type(8))) short bf16x8;
typedef __attribute__((ext_vector_type(4))) short bf16x4;
typedef __attribute__((ext_vector_type(4))) float f32x4;

__device__ __forceinline__ float bf2f(ushort u) {
  union { unsigned int i; float f; } v; v.i = ((unsigned int)u) << 16; return v.f;
}
__device__ __forceinline__ ushort f2bf(float f) {
  union { float f; unsigned int i; } v; v.f = f;
  unsigned int x = v.i;
  unsigned int r = (x + 0x7fffu + ((x >> 16) & 1u)) >> 16;
  return (ushort)r;
}

// ---------------------------------------------------------------- utilities
__global__ void zero_f32(float* p, int n) {
  int i = blockIdx.x * 256 + threadIdx.x;
  if (i < n) p[i] = 0.f;
}

// Pack W[co][ci][ky][kx] (fp32) -> Wp[tap][cic][cf][lane][8] (bf16)
__global__ void pack_w(const float* __restrict__ W, ushort* __restrict__ Wp, int Cin) {
  int ncic = Cin >> 5;
  int total = 9 * ncic * 8 * 64 * 8;
  for (int idx = blockIdx.x * 256 + threadIdx.x; idx < total; idx += gridDim.x * 256) {
    int j = idx & 7;
    int l = (idx >> 3) & 63;
    int cf = (idx >> 9) & 7;
    int rest = idx >> 12;
    int cic = rest % ncic;
    int tap = rest / ncic;
    int co = cf * 16 + (l & 15);
    int ci = cic * 32 + ((l >> 4) * 8) + j;
    int ky = tap / 3, kx = tap % 3;
    Wp[idx] = f2bf(W[((co * Cin + ci) * 3 + ky) * 3 + kx]);
  }
}

// NCHW fp32 [8][64][65536] -> NHWC bf16 [8][65536][64]
__global__ __launch_bounds__(256)
void nchw2nhwc(const float* __restrict__ in, ushort* __restrict__ out) {
  const int n  = blockIdx.y;
  const int p0 = blockIdx.x << 6;
  const int tid = threadIdx.x;
  __shared__ ushort t[64 * 72];
  {
    int c  = tid >> 2;
    int pq = (tid & 3) << 4;
    const float* ip = in + (((size_t)(n * 64 + c)) << 16) + p0 + pq;
#pragma unroll
    for (int k = 0; k < 4; ++k) {
      float4 f = *(const float4*)(ip + k * 4);
      int p = pq + k * 4;
      t[(p + 0) * 72 + c] = f2bf(f.x);
      t[(p + 1) * 72 + c] = f2bf(f.y);
      t[(p + 2) * 72 + c] = f2bf(f.z);
      t[(p + 3) * 72 + c] = f2bf(f.w);
    }
  }
  __syncthreads();
#pragma unroll
  for (int k = 0; k < 2; ++k) {
    int id = k * 256 + tid;
    int cj = id & 7, p = id >> 3;
    bf16x8 v = *(const bf16x8*)&t[p * 72 + cj * 8];
    *(bf16x8*)(out + ((((size_t)n << 16) + p0 + p) << 6) + cj * 8) = v;
  }
}

__device__ __forceinline__ bf16x8 bnrelu8(bf16x8 v, const float* __restrict__ coef, int c0) {
  float4 a0 = *(const float4*)(coef + c0);
  float4 a1 = *(const float4*)(coef + c0 + 4);
  float4 b0 = *(const float4*)(coef + 128 + c0);
  float4 b1 = *(const float4*)(coef + 128 + c0 + 4);
  bf16x8 r;
  r[0] = (short)f2bf(fmaxf(a0.x * bf2f((ushort)v[0]) + b0.x, 0.f));
  r[1] = (short)f2bf(fmaxf(a0.y * bf2f((ushort)v[1]) + b0.y, 0.f));
  r[2] = (short)f2bf(fmaxf(a0.z * bf2f((ushort)v[2]) + b0.z, 0.f));
  r[3] = (short)f2bf(fmaxf(a0.w * bf2f((ushort)v[3]) + b0.w, 0.f));
  r[4] = (short)f2bf(fmaxf(a1.x * bf2f((ushort)v[4]) + b1.x, 0.f));
  r[5] = (short)f2bf(fmaxf(a1.y * bf2f((ushort)v[5]) + b1.y, 0.f));
  r[6] = (short)f2bf(fmaxf(a1.z * bf2f((ushort)v[6]) + b1.z, 0.f));
  r[7] = (short)f2bf(fmaxf(a1.w * bf2f((ushort)v[7]) + b1.w, 0.f));
  return r;
}

// ---------------------------------------------------------------- conv core (NHWC)
// src NHWC bf16 [n][H*W][Cin]; out NHWC bf16 [n][H*W][128].
// Block: 512 threads = 8 waves = 4 co-quarters (cg, 2 cf each) x 2 rows (wy).
// LDS staging double buffer [4 rows][66 xt][32 ci], 16B-chunk XOR swizzle:
//   chunk' = chunk ^ ((chunk>>3)&7)  -- kills the 4-way phase-group conflict
//   on B-frag ds_read_b128 while keeping the linear write conflict-free.
template<int MODE>
__global__ __launch_bounds__(512, 4)
void conv_mfma(const ushort* __restrict__ src, const ushort* __restrict__ Wp,
               const float* __restrict__ bias, const float* __restrict__ coef,
               ushort* __restrict__ out, float* __restrict__ sSum, float* __restrict__ sSsq,
               int Cin, int H, int W)
{
  const int ncic = Cin >> 5;
  const int x0 = blockIdx.x << 6;
  const int y0 = blockIdx.y << 1;
  const int n  = blockIdx.z;
  const int tid = threadIdx.x;
  const int wv = tid >> 6, l = tid & 63, l15 = l & 15, l4 = l >> 4;
  const int cg = wv >> 1;      // co quarter 0..3
  const int wy = wv & 1;       // output row

  __shared__ __align__(16) ushort smem[2 * 8448];   // 2 x [4 rows][66 xt][32 ci]

  const size_t HW = (size_t)H * W;
  const ushort* srcn = src + (size_t)n * HW * Cin;

  // chunk geometry: i = it*512 + tid (i < 1056); cj=i&3, p=i>>2, row=p/66, xt=p%66
  int off[3];
#pragma unroll
  for (int it = 0; it < 3; ++it) {
    int i = it * 512 + tid;
    int cj = i & 3, p = i >> 2;
    int row = p / 66, xt = p - row * 66;
    int ry = y0 + row - 1, gx = x0 + xt - 1;
    bool ok = (i < 1056) && ((unsigned)ry < (unsigned)H) && ((unsigned)gx < (unsigned)W);
    off[it] = ok ? (int)((ry * W + gx) * Cin + (cj << 3)) : -1;
  }

  f32x4 acc[2][4];
#pragma unroll
  for (int f = 0; f < 2; ++f)
#pragma unroll
    for (int xf = 0; xf < 4; ++xf) acc[f][xf] = (f32x4){0.f, 0.f, 0.f, 0.f};

  bf16x8 st[3];

  auto LOADREG = [&](int cic) {
#pragma unroll
    for (int it = 0; it < 3; ++it) {
      bf16x8 v = {};
      if (off[it] >= 0) v = *(const bf16x8*)(srcn + off[it] + (cic << 5));
      st[it] = v;
    }
  };

  auto WRITE = [&](ushort* buf, int cic) {
#pragma unroll
    for (int it = 0; it < 3; ++it) {
      if (it < 2 || tid < 32) {
        int i = it * 512 + tid;
        bf16x8 v = st[it];
        if (MODE == 1) {
          if (off[it] >= 0) v = bnrelu8(v, coef, (cic << 5) + ((i & 3) << 3));
        }
        int ch = i ^ ((i >> 3) & 7);     // bank swizzle
        *(bf16x8*)(buf + (ch << 3)) = v;
      }
    }
  };

  auto COMPUTE = [&](const ushort* buf, int cic) {
    const ushort* wp = Wp + ((size_t)cic * 8 + (cg << 1)) * 512 + ((size_t)l << 3);
    const size_t tstride = (size_t)ncic * 4096;
#pragma unroll
    for (int tap = 0; tap < 9; ++tap) {
      const int ky = tap / 3, kx = tap % 3;
      bf16x8 a0 = *(const bf16x8*)(wp + (size_t)tap * tstride);
      bf16x8 a1 = *(const bf16x8*)(wp + (size_t)tap * tstride + 512);
      bf16x8 b[4];
#pragma unroll
      for (int xf = 0; xf < 4; ++xf) {
        int ch = ((((wy + ky) * 66 + (xf << 4) + kx + l15) << 2) | l4);
        ch ^= (ch >> 3) & 7;             // bank swizzle
        b[xf] = *(const bf16x8*)(buf + (ch << 3));
      }
#pragma unroll
      for (int xf = 0; xf < 4; ++xf) {
        acc[0][xf] = __builtin_amdgcn_mfma_f32_16x16x32_bf16(a0, b[xf], acc[0][xf], 0, 0, 0);
        acc[1][xf] = __builtin_amdgcn_mfma_f32_16x16x32_bf16(a1, b[xf], acc[1][xf], 0, 0, 0);
      }
    }
  };

  LOADREG(0);
  WRITE(smem, 0);
  __syncthreads();

  int cur = 0;
  for (int cic = 0; cic < ncic; ++cic) {
    if (cic + 1 < ncic) LOADREG(cic + 1);
    COMPUTE(smem + cur * 8448, cic);
    if (cic + 1 < ncic) WRITE(smem + (cur ^ 1) * 8448, cic + 1);
    __syncthreads();
    cur ^= 1;
  }

  // ------------- epilogue: bias, stats, NHWC store via LDS transpose
  float smv[2][4] = {{0.f}}, sqv[2][4] = {{0.f}};
  ushort* eps = smem;   // [x64][co 136]
  for (int yr = 0; yr < 2; ++yr) {
    __syncthreads();
    if (wy == yr) {
#pragma unroll
      for (int f = 0; f < 2; ++f) {
        const int col = (cg << 5) + (f << 4) + (l4 << 2);
        float4 bv = *(const float4*)(bias + col);
#pragma unroll
        for (int xf = 0; xf < 4; ++xf) {
          float v0 = acc[f][xf][0] + bv.x;
          float v1 = acc[f][xf][1] + bv.y;
          float v2 = acc[f][xf][2] + bv.z;
          float v3 = acc[f][xf][3] + bv.w;
          smv[f][0] += v0; sqv[f][0] += v0 * v0;
          smv[f][1] += v1; sqv[f][1] += v1 * v1;
          smv[f][2] += v2; sqv[f][2] += v2 * v2;
          smv[f][3] += v3; sqv[f][3] += v3 * v3;
          bf16x4 u;
          u[0] = (short)f2bf(v0); u[1] = (short)f2bf(v1);
          u[2] = (short)f2bf(v2); u[3] = (short)f2bf(v3);
          *(bf16x4*)&eps[((xf << 4) + l15) * 136 + col] = u;
        }
      }
    }
    __syncthreads();
    {
      const int xx = tid >> 3, c0 = (tid & 7) << 4;
      ushort* op = out + ((size_t)n * HW + (size_t)(y0 + yr) * W + x0 + xx) * 128 + c0;
      *(bf16x8*)op       = *(const bf16x8*)&eps[xx * 136 + c0];
      *(bf16x8*)(op + 8) = *(const bf16x8*)&eps[xx * 136 + c0 + 8];
    }
  }

  const int rep = (int)((blockIdx.z * gridDim.y + blockIdx.y) * gridDim.x + blockIdx.x) & 31;
#pragma unroll
  for (int f = 0; f < 2; ++f)
#pragma unroll
    for (int j = 0; j < 4; ++j) {
      float s = smv[f][j], q = sqv[f][j];
#pragma unroll
      for (int o = 1; o < 16; o <<= 1) { s += __shfl_xor(s, o); q += __shfl_xor(q, o); }
      if (l15 == 0) {
        int co = (cg << 5) + (f << 4) + (l4 << 2) + j;
        atomicAdd(&sSum[rep * 128 + co], s);
        atomicAdd(&sSsq[rep * 128 + co], q);
      }
    }
}

// ---------------------------------------------------------------- BN finalize
__global__ void bn_finalize(const float* __restrict__ sSum, const float* __restrict__ sSsq,
                            const float* __restrict__ g, const float* __restrict__ be,
                            float* __restrict__ coef, float invN)
{
  int c = threadIdx.x;  // 128
  float S = 0.f, Q = 0.f;
  for (int r = 0; r < 32; ++r) { S += sSum[r * 128 + c]; Q += sSsq[r * 128 + c]; }
  float m = S * invN;
  float v = Q * invN - m * m;
  float a = g[c] / sqrtf(v + 1e-5f);
  coef[c] = a;
  coef[128 + c] = be[c] - m * a;
}

// ---------------------------------------------------------------- fused bn_relu + skip out (NCHW fp32) + DWT (NHWC bf16)
__global__ __launch_bounds__(256)
void skip_dwt2(const ushort* __restrict__ skipRaw, const float* __restrict__ coef,
               float* __restrict__ outSkip, ushort* __restrict__ dwt)
{
  const int x0 = blockIdx.x << 6;
  const int oy = blockIdx.y;
  const int n  = blockIdx.z >> 2;
  const int ct = blockIdx.z & 3;
  const int y0 = oy << 1;
  const int tid = threadIdx.x;
  __shared__ float t32[32 * 2 * 68];

#pragma unroll
  for (int it = 0; it < 2; ++it) {
    int i = it * 256 + tid;
    int cj = i & 3, x = (i >> 2) & 63, r = i >> 8;
    int c0 = (ct << 5) + (cj << 3);
    bf16x8 v = *(const bf16x8*)(skipRaw + (((size_t)n << 16) + (size_t)(y0 + r) * 256 + x0 + x) * 128 + c0);
    float4 a0 = *(const float4*)(coef + c0);
    float4 a1 = *(const float4*)(coef + c0 + 4);
    float4 b0 = *(const float4*)(coef + 128 + c0);
    float4 b1 = *(const float4*)(coef + 128 + c0 + 4);
    float av[8] = {a0.x, a0.y, a0.z, a0.w, a1.x, a1.y, a1.z, a1.w};
    float bv[8] = {b0.x, b0.y, b0.z, b0.w, b1.x, b1.y, b1.z, b1.w};
    int cl = cj << 3;
#pragma unroll
    for (int k = 0; k < 8; ++k)
      t32[((cl + k) * 2 + r) * 68 + x] = fmaxf(av[k] * bf2f((ushort)v[k]) + bv[k], 0.f);
  }
  __syncthreads();

  {
    int c = tid >> 3, x8 = (tid & 7) << 3;
    float* op = outSkip + (((size_t)(n * 128 + (ct << 5) + c)) << 16) + (size_t)y0 * 256 + x0 + x8;
#pragma unroll
    for (int r = 0; r < 2; ++r) {
      float4 r0 = *(const float4*)&t32[(c * 2 + r) * 68 + x8];
      float4 r1 = *(const float4*)&t32[(c * 2 + r) * 68 + x8 + 4];
      *(float4*)(op + (size_t)r * 256) = r0;
      *(float4*)(op + (size_t)r * 256 + 4) = r1;
    }
  }

  if (tid < 128) {
    int cj = tid & 3, ox = tid >> 2;
    int cl = cj << 3;
    bf16x8 oA, oH, oV, oD;
#pragma unroll
    for (int k = 0; k < 8; ++k) {
      int c = cl + k;
      float p00 = t32[(c * 2 + 0) * 68 + 2 * ox];
      float p01 = t32[(c * 2 + 0) * 68 + 2 * ox + 1];
      float p10 = t32[(c * 2 + 1) * 68 + 2 * ox];
      float p11 = t32[(c * 2 + 1) * 68 + 2 * ox + 1];
      oA[k] = (short)f2bf((p00 + p01 + p10 + p11) * 0.5f);
      oH[k] = (short)f2bf((p00 + p01 - p10 - p11) * 0.5f);
      oV[k] = (short)f2bf((p00 - p01 + p10 - p11) * 0.5f);
      oD[k] = (short)f2bf((p00 - p01 - p10 + p11) * 0.5f);
    }
    size_t db = ((size_t)n * 16384 + (size_t)oy * 128 + (x0 >> 1) + ox) * 512 + (ct << 5) + cl;
    *(bf16x8*)(dwt + db)       = oA;
    *(bf16x8*)(dwt + db + 128) = oH;
    *(bf16x8*)(dwt + db + 256) = oV;
    *(bf16x8*)(dwt + db + 384) = oD;
  }
}

// ---------------------------------------------------------------- bn_relu + NHWC->NCHW fp32 out
__global__ __launch_bounds__(256)
void bn_transpose_out(const ushort* __restrict__ src, const float* __restrict__ coef,
                      float* __restrict__ dst, int H, int W)
{
  const int n  = blockIdx.z >> 2;
  const int cc = blockIdx.z & 3;
  const int x0 = blockIdx.x << 6;
  const int y  = blockIdx.y;
  const int tid = threadIdx.x;
  __shared__ float t[32 * 68];
  const size_t HW = (size_t)H * W;
  {
    int p = tid >> 2, cj = tid & 3;
    int c0 = (cc << 5) + (cj << 3);
    bf16x8 v = *(const bf16x8*)(src + ((size_t)n * HW + (size_t)y * W + x0 + p) * 128 + c0);
    float4 a0 = *(const float4*)(coef + c0);
    float4 a1 = *(const float4*)(coef + c0 + 4);
    float4 b0 = *(const float4*)(coef + 128 + c0);
    float4 b1 = *(const float4*)(coef + 128 + c0 + 4);
    int cl = cj << 3;
    t[(cl + 0) * 68 + p] = fmaxf(a0.x * bf2f((ushort)v[0]) + b0.x, 0.f);
    t[(cl + 1) * 68 + p] = fmaxf(a0.y * bf2f((ushort)v[1]) + b0.y, 0.f);
    t[(cl + 2) * 68 + p] = fmaxf(a0.z * bf2f((ushort)v[2]) + b0.z, 0.f);
    t[(cl + 3) * 68 + p] = fmaxf(a0.w * bf2f((ushort)v[3]) + b0.w, 0.f);
    t[(cl + 4) * 68 + p] = fmaxf(a1.x * bf2f((ushort)v[4]) + b1.x, 0.f);
    t[(cl + 5) * 68 + p] = fmaxf(a1.y * bf2f((ushort)v[5]) + b1.y, 0.f);
    t[(cl + 6) * 68 + p] = fmaxf(a1.z * bf2f((ushort)v[6]) + b1.z, 0.f);
    t[(cl + 7) * 68 + p] = fmaxf(a1.w * bf2f((ushort)v[7]) + b1.w, 0.f);
  }
  __syncthreads();
  {
    int c = tid >> 3, x8 = (tid & 7) << 3;
    float4 r0 = *(const float4*)&t[c * 68 + x8];
    float4 r1 = *(const float4*)&t[c * 68 + x8 + 4];
    float* op = dst + ((size_t)(n * 128 + (cc << 5) + c)) * HW + (size_t)y * W + x0 + x8;
    *(float4*)op = r0;
    *(float4*)(op + 4) = r1;
  }
}

// ---------------------------------------------------------------- launch
extern "C" void kernel_launch(void* const* d_in, const int* in_sizes, int n_in,
                              void* d_out, int out_size, void* d_ws, size_t ws_size,
                              hipStream_t stream)
{
  const float* input = (const float*)d_in[0];
  const float* W1  = (const float*)d_in[1];
  const float* b1  = (const float*)d_in[2];
  const float* g1  = (const float*)d_in[3];
  const float* be1 = (const float*)d_in[4];
  const float* W2  = (const float*)d_in[5];
  const float* b2  = (const float*)d_in[6];
  const float* g2  = (const float*)d_in[7];
  const float* be2 = (const float*)d_in[8];
  const float* W3  = (const float*)d_in[9];
  const float* b3  = (const float*)d_in[10];
  const float* g3  = (const float*)d_in[11];
  const float* be3 = (const float*)d_in[12];

  char* ws = (char*)d_ws;
  ushort* h_raw    = (ushort*)(ws + 0);            // NHWC [8][65536][128]
  ushort* skip_raw = (ushort*)(ws + 134217728);    // NHWC [8][65536][128]
  ushort* dwt      = (ushort*)(ws + 268435456);    // NHWC [8][16384][512]
  ushort* in_nhwc  = (ushort*)(ws + 268435456);    // NHWC [8][65536][64] (aliased w/ dwt)
  ushort* raw3     = (ushort*)(ws + 402653184);    // NHWC [8][16384][128]
  float*  stats    = (float*)(ws + 436207616);
  float*  s1 = stats,          *q1 = stats + 4096;
  float*  s2 = stats + 8192,   *q2 = stats + 12288;
  float*  s3 = stats + 16384,  *q3 = stats + 20480;
  float*  coef = (float*)(ws + 436305920);
  float*  c1 = coef, *c2 = coef + 256, *c3 = coef + 512;
  ushort* Wp1 = (ushort*)(ws + 436308992);
  ushort* Wp2 = (ushort*)(ws + 436456448);
  ushort* Wp3 = (ushort*)(ws + 436751360);

  zero_f32<<<96, 256, 0, stream>>>(stats, 24576);
  pack_w<<<288, 256, 0, stream>>>(W1, Wp1, 64);
  pack_w<<<576, 256, 0, stream>>>(W2, Wp2, 128);
  pack_w<<<2304, 256, 0, stream>>>(W3, Wp3, 512);
  nchw2nhwc<<<dim3(1024, 8), 256, 0, stream>>>(input, in_nhwc);

  conv_mfma<0><<<dim3(4, 128, 8), 512, 0, stream>>>(in_nhwc, Wp1, b1, nullptr,
                                                    h_raw, s1, q1, 64, 256, 256);
  bn_finalize<<<1, 128, 0, stream>>>(s1, q1, g1, be1, c1, 1.f / 524288.f);

  conv_mfma<1><<<dim3(4, 128, 8), 512, 0, stream>>>(h_raw, Wp2, b2, c1,
                                                    skip_raw, s2, q2, 128, 256, 256);
  bn_finalize<<<1, 128, 0, stream>>>(s2, q2, g2, be2, c2, 1.f / 524288.f);

  skip_dwt2<<<dim3(4, 128, 32), 256, 0, stream>>>(skip_raw, c2, (float*)d_out, dwt);

  conv_mfma<0><<<dim3(2, 64, 8), 512, 0, stream>>>(dwt, Wp3, b3, nullptr,
                                                   raw3, s3, q3, 512, 128, 128);
  bn_finalize<<<1, 128, 0, stream>>>(s3, q3, g3, be3, c3, 1.f / 131072.f);

  bn_transpose_out<<<dim3(2, 128, 32), 256, 0, stream>>>(raw3, c3, (float*)d_out + 67108864, 128, 128);
}